// Round 9
// baseline (243.387 us; speedup 1.0000x reference)
//
#include <hip/hip_runtime.h>
#include <hip/hip_bf16.h>

// B=4, L=2048, D=1024, H=16, HD=64. fp32 in/out.
// conv_fused (W/K/V fp32->bf16, V transposed, XOR-swizzle baked into global layout) ;
// attn (flash S^T form, 32x32 MFMA, KVBLK=64, TRIPLE-buffered LDS + counted vmcnt(4):
//       tile-t DMA issued 2 iters early, next tile's loads stay in flight across s_barrier;
//       in-register softmax via cvt_pk_bf16 + permlane32_swap, VALU lsum) ;
// proj GEMM (BK=64, swizzled LDS, async gld dbuf, XCD-local m-panel remap).
// Kb/Vb scratch lives in d_out (dead before proj writes Y).

#define B_  4
#define L_  2048
#define D_  1024
#define H_  16

typedef float  f32x4  __attribute__((ext_vector_type(4)));
typedef float  f32x16 __attribute__((ext_vector_type(16)));
typedef short  bf16x8 __attribute__((ext_vector_type(8)));
typedef short  bf16x4 __attribute__((ext_vector_type(4)));

__device__ inline unsigned short f2bf(float x) {          // RNE
    union { float f; unsigned u; } v; v.f = x;
    unsigned r = v.u + 0x7FFFu + ((v.u >> 16) & 1u);
    return (unsigned short)(r >> 16);
}
__device__ inline float fast_exp2(float x) {
#if __has_builtin(__builtin_amdgcn_exp2f)
    return __builtin_amdgcn_exp2f(x);
#else
    return exp2f(x);
#endif
}
__device__ inline bf16x8 pack8s(float4 a, float4 b, float s) {
    bf16x8 r;
    r[0] = (short)f2bf(a.x * s); r[1] = (short)f2bf(a.y * s);
    r[2] = (short)f2bf(a.z * s); r[3] = (short)f2bf(a.w * s);
    r[4] = (short)f2bf(b.x * s); r[5] = (short)f2bf(b.y * s);
    r[6] = (short)f2bf(b.z * s); r[7] = (short)f2bf(b.w * s);
    return r;
}
__device__ inline unsigned cvtpk(float lo, float hi) {    // dword: lo16=bf16(lo), hi16=bf16(hi)
    unsigned r;
    asm("v_cvt_pk_bf16_f32 %0, %1, %2" : "=v"(r) : "v"(lo), "v"(hi));
    return r;
}
#define PSWAP(a, b) asm("v_permlane32_swap_b32 %0, %1" : "+v"(a), "+v"(b))

__device__ inline f32x16 zero16() {
    f32x16 z;
    #pragma unroll
    for (int i = 0; i < 16; ++i) z[i] = 0.f;
    return z;
}
__device__ inline void gld16(const void* g, void* l) {    // async global->LDS, 16B/lane
    __builtin_amdgcn_global_load_lds(
        (const __attribute__((address_space(1))) void*)g,
        (__attribute__((address_space(3))) void*)l, 16, 0, 0);
}

// ---------------- fused W/K/V fp32 -> bf16 conversions ----------------
// blocks [0,1024): W ; [1024,5120): K ; [5120,7168): V-transpose.
__global__ __launch_bounds__(256) void conv_fused(const float* __restrict__ W,
                                                  unsigned short* __restrict__ Wb,
                                                  const float* __restrict__ K,
                                                  unsigned short* __restrict__ Kb,
                                                  const float* __restrict__ V,
                                                  unsigned short* __restrict__ Vb) {
    __shared__ __align__(16) unsigned short T[64 * 72];  // convv transpose, [d][key] pad 72
    const int bid = blockIdx.x;
    const int tid = threadIdx.x;

    if (bid < 1024) {
        // ---- W ----
        int i = (bid * 256 + tid) * 4;
        float4 v = *(const float4*)&W[i];
        bf16x4 o;
        o[0] = (short)f2bf(v.x); o[1] = (short)f2bf(v.y);
        o[2] = (short)f2bf(v.z); o[3] = (short)f2bf(v.w);
        *(bf16x4*)&Wb[i] = o;
    } else if (bid < 5120) {
        // ---- K: [b,key,h,d], d-chunk XOR swizzle ----
        int o = (bid - 1024) * 256 + tid;            // octet index
        int d8 = o & 7; int h = (o >> 3) & 15; int key = (o >> 7) & 2047; int b = o >> 18;
        size_t base = ((size_t)(b * L_ + key) * H_ + h) * 64;
        const float* p = K + base + d8 * 8;
        float4 a = *(const float4*)p, c = *(const float4*)(p + 4);
        bf16x8 r;
        r[0] = (short)f2bf(a.x); r[1] = (short)f2bf(a.y); r[2] = (short)f2bf(a.z); r[3] = (short)f2bf(a.w);
        r[4] = (short)f2bf(c.x); r[5] = (short)f2bf(c.y); r[6] = (short)f2bf(c.z); r[7] = (short)f2bf(c.w);
        *(bf16x8*)&Kb[base + ((d8 * 8) ^ ((key & 7) * 8))] = r;
    } else {
        // ---- V transposed [b,h,d,key], coalesced reads ----
        int vb_ = bid - 5120;
        int kb_ = vb_ & 31, bh = vb_ >> 5;
        int b = bh >> 4, h = bh & 15, k0 = kb_ * 64;
        int kl = tid >> 4;
        int d4 = (tid & 15) * 4;
        #pragma unroll
        for (int pp = 0; pp < 4; ++pp) {
            int key = pp * 16 + kl;
            const float* p = V + ((size_t)(b * L_ + k0 + key)) * D_ + h * 64 + d4;
            float4 v = *(const float4*)p;    // coalesced: 16 lanes cover one 256B row
            T[(d4 + 0) * 72 + key] = f2bf(v.x);
            T[(d4 + 1) * 72 + key] = f2bf(v.y);
            T[(d4 + 2) * 72 + key] = f2bf(v.z);
            T[(d4 + 3) * 72 + key] = f2bf(v.w);
        }
        __syncthreads();
        #pragma unroll
        for (int i = 0; i < 2; ++i) {
            int c = i * 256 + tid; int d = c >> 3, ch = c & 7;
            bf16x8 v = *(const bf16x8*)&T[d * 72 + ch * 8];
            *(bf16x8*)&Vb[((size_t)(b * H_ + h) * 64 + d) * L_ + k0 + ((ch ^ (d & 7)) * 8)] = v;
        }
    }
}

// ---------------- flash attention (S^T form, 32x32 MFMA, KVBLK=64), 128 q/block -------------
// 256 threads / 4 waves. KV tiles triple-buffered in LDS (48 KB). Pipeline: tile t's DMA is
// issued at iter t-2; per iter: s_waitcnt vmcnt(4) (own tile-t loads done, tile-t+1's 4 loads
// stay in flight) -> s_barrier (all waves' tile-t writes visible; all done reading buf t-1)
// -> ISSUE(t+2) into buf (t+2)%3 -> compute(t). Softmax: cvt_pk + permlane32_swap, VALU lsum.
__global__ __launch_bounds__(256, 4) void attn_kernel(const float* __restrict__ Qg,
                                                      const unsigned short* __restrict__ Kb,
                                                      const unsigned short* __restrict__ Vb,
                                                      unsigned short* __restrict__ Og) {
    __shared__ __align__(16) unsigned short Ks[3][64 * 64];   // [key][d^swz]
    __shared__ __align__(16) unsigned short Vt[3][64 * 64];   // [d][key^swz]

    const int tid  = threadIdx.x;
    const int w    = tid >> 6;
    const int lane = tid & 63;
    const int l31  = lane & 31;
    const int hl   = lane >> 5;
    const int r7   = l31 & 7;

    // XCD swizzle: 16 q-blocks of one (b,h) on one XCD
    const int x   = blockIdx.x;
    const int idx = x >> 3;
    const int bh  = (x & 7) * 8 + (idx & 7);
    const int qb  = idx >> 3;
    const int bz  = bh >> 4;
    const int h   = bh & 15;
    const int q0  = qb * 128;

    const float qscale = 0.04508422f;           // log2(e)/32
    // Q as B-operand: lane needs Q[q0+w*32+l31][dstep*16 + hl*8 + 0..7]
    bf16x8 bq[4];
    {
        const int qrow = q0 + w * 32 + l31;
        const float* qp = Qg + ((size_t)(bz * L_ + qrow)) * D_ + h * 64 + hl * 8;
        #pragma unroll
        for (int dstep = 0; dstep < 4; ++dstep)
            bq[dstep] = pack8s(*(const float4*)(qp + dstep * 16),
                               *(const float4*)(qp + dstep * 16 + 4), qscale);
    }

    f32x16 o[2];
    o[0] = zero16(); o[1] = zero16();
    float lsum = 0.f;

    const unsigned short* Kbh = Kb + ((size_t)bz * L_ * H_ + h) * 64;  // + key*(H_*64)
    const unsigned short* Vbh = Vb + (size_t)(bz * H_ + h) * 64 * L_;  // + d*L_

    // 4 gld16 per thread per tile (2 K + 2 V).
    #define ISSUE(T, BUF)                                                           \
        {                                                                           \
            int k0_ = (T) * 64;                                                     \
            _Pragma("unroll")                                                       \
            for (int i = 0; i < 2; ++i) {                                           \
                int c = i * 256 + tid; int rr = c >> 3, jj = c & 7;                 \
                gld16(Kbh + (size_t)(k0_ + rr) * (H_ * 64) + jj * 8,                \
                      (char*)Ks[BUF] + (i * 256 + w * 64) * 16);                    \
                gld16(Vbh + (size_t)rr * L_ + k0_ + jj * 8,                         \
                      (char*)Vt[BUF] + (i * 256 + w * 64) * 16);                    \
            }                                                                       \
        }

    #define COMP(KSP, VTP)                                                          \
        {                                                                           \
            const unsigned short* ks = (KSP);                                       \
            const unsigned short* vt = (VTP);                                       \
            _Pragma("unroll")                                                       \
            for (int kk = 0; kk < 2; ++kk) {                                        \
                f32x16 s = zero16();                                                \
                _Pragma("unroll")                                                   \
                for (int dstep = 0; dstep < 4; ++dstep) {                           \
                    bf16x8 kf = *(const bf16x8*)&ks[(kk * 32 + l31) * 64 +          \
                                                    ((((dstep << 1) | hl) ^ r7) << 3)]; \
                    s = __builtin_amdgcn_mfma_f32_32x32x16_bf16(kf, bq[dstep], s, 0, 0, 0); \
                }                                                                   \
                float p_[16];                                                       \
                _Pragma("unroll")                                                   \
                for (int r = 0; r < 16; ++r) p_[r] = fast_exp2(s[r]);               \
                lsum += ((p_[0] + p_[1]) + (p_[2] + p_[3])) + ((p_[4] + p_[5]) + (p_[6] + p_[7])) \
                      + ((p_[8] + p_[9]) + (p_[10] + p_[11])) + ((p_[12] + p_[13]) + (p_[14] + p_[15])); \
                unsigned pk_[8];                                                    \
                _Pragma("unroll")                                                   \
                for (int j = 0; j < 8; ++j) pk_[j] = cvtpk(p_[2 * j], p_[2 * j + 1]); \
                PSWAP(pk_[0], pk_[2]); PSWAP(pk_[1], pk_[3]);                       \
                PSWAP(pk_[4], pk_[6]); PSWAP(pk_[5], pk_[7]);                       \
                union { unsigned u[4]; bf16x8 v; } a0_, a1_;                        \
                a0_.u[0] = pk_[0]; a0_.u[1] = pk_[1]; a0_.u[2] = pk_[2]; a0_.u[3] = pk_[3]; \
                a1_.u[0] = pk_[4]; a1_.u[1] = pk_[5]; a1_.u[2] = pk_[6]; a1_.u[3] = pk_[7]; \
                _Pragma("unroll")                                                   \
                for (int kh = 0; kh < 2; ++kh) {                                    \
                    const bf16x8 pf = kh ? a1_.v : a0_.v;                           \
                    const int kk2 = kk * 2 + kh;                                    \
                    bf16x8 v0 = *(const bf16x8*)&vt[(l31) * 64 +                    \
                                                    ((((kk2 << 1) | hl) ^ r7) << 3)]; \
                    bf16x8 v1 = *(const bf16x8*)&vt[(32 + l31) * 64 +               \
                                                    ((((kk2 << 1) | hl) ^ r7) << 3)]; \
                    o[0] = __builtin_amdgcn_mfma_f32_32x32x16_bf16(pf, v0, o[0], 0, 0, 0); \
                    o[1] = __builtin_amdgcn_mfma_f32_32x32x16_bf16(pf, v1, o[1], 0, 0, 0); \
                }                                                                   \
            }                                                                       \
        }

    ISSUE(0, 0)
    ISSUE(1, 1)

    #pragma unroll 3
    for (int t = 0; t < 30; ++t) {
        asm volatile("s_waitcnt vmcnt(4)" ::: "memory");   // own tile-t loads done; t+1 in flight
        __builtin_amdgcn_s_barrier();                      // all waves' tile-t writes visible
        const int b2 = (t + 2) % 3;
        ISSUE(t + 2, b2)                                   // overwrites buf (t-1)%3 (WAR-safe)
        const int bt = t % 3;
        COMP(Ks[bt], Vt[bt])
    }
    // t = 30 (30%3 == 0): tile 31's loads still in flight
    asm volatile("s_waitcnt vmcnt(4)" ::: "memory");
    __builtin_amdgcn_s_barrier();
    COMP(Ks[0], Vt[0])
    // t = 31: tile 31 lives in buf 31%3 == 1 (issued at t=29). Drain and compute buf1.
    asm volatile("s_waitcnt vmcnt(0)" ::: "memory");
    __builtin_amdgcn_s_barrier();
    COMP(Ks[1], Vt[1])

    // ---- deferred row-sum completion + scaled store ----
    float tot = lsum + __shfl_xor(lsum, 32);    // lane holds full sum for q = l31
    float inv = 1.0f / tot;
    const size_t rowb0 = ((size_t)(bz * L_ + q0 + w * 32)) * D_ + h * 64;
    #pragma unroll
    for (int r = 0; r < 16; ++r) {
        const int qloc = (r & 3) + 8 * (r >> 2) + 4 * hl;
        const float invr = __shfl(inv, qloc);
        unsigned short* op = Og + rowb0 + (size_t)qloc * D_;
        op[l31]      = f2bf(o[0][r] * invr);
        op[32 + l31] = f2bf(o[1][r] * invr);
    }
}

// ---------------- projection: Y = O @ W^T + b, BK=64 swizzled, async dbuf ----------------
// 1D grid, XCD-local remap: all 8 n-blocks of one m-block share an XCD -> A-panel L2-resident.
__global__ __launch_bounds__(256, 2) void proj_kernel(const unsigned short* __restrict__ Og,
                                                      const unsigned short* __restrict__ Wb,
                                                      const float* __restrict__ bias,
                                                      float* __restrict__ Yg) {
    __shared__ unsigned short As[2][128 * 64];  // [row][64 shorts], chunk slot p holds octet p^(row&7)
    __shared__ unsigned short Bs[2][128 * 64];

    const int tid  = threadIdx.x;
    const int w    = tid >> 6;
    const int lane = tid & 63;
    const int l16  = lane & 15;
    const int quad = lane >> 4;
    const int wm   = w & 1, wn = w >> 1;

    const int bid = blockIdx.x;                 // 0..511
    const int jj_ = bid >> 3;                   // 0..63
    const int mb  = (bid & 7) + 8 * (jj_ >> 3); // 0..63 : same-m blocks share XCD
    const int nb  = jj_ & 7;                    // 0..7
    const int m0 = mb * 128;
    const int n0 = nb * 128;

    f32x4 acc[4][4];
    #pragma unroll
    for (int i = 0; i < 4; ++i)
        #pragma unroll
        for (int j = 0; j < 4; ++j) acc[i][j] = (f32x4){0.f, 0.f, 0.f, 0.f};

    #define PISSUE(T, BUF)                                                          \
        {                                                                           \
            int kt_ = (T) * 64;                                                     \
            _Pragma("unroll")                                                       \
            for (int i = 0; i < 4; ++i) {                                           \
                int c = i * 256 + tid; int row = c >> 3, p = c & 7;                 \
                int j = p ^ (row & 7);                                              \
                gld16(&Og[(size_t)(m0 + row) * 1024 + kt_ + j * 8],                 \
                      (char*)As[BUF] + (i * 256 + w * 64) * 16);                    \
                gld16(&Wb[(size_t)(n0 + row) * 1024 + kt_ + j * 8],                 \
                      (char*)Bs[BUF] + (i * 256 + w * 64) * 16);                    \
            }                                                                       \
        }

    PISSUE(0, 0)

    for (int t = 0; t < 16; ++t) {
        __syncthreads();
        if (t < 15) PISSUE(t + 1, (t + 1) & 1)
        const unsigned short* as = As[t & 1];
        const unsigned short* bs = Bs[t & 1];

        #pragma unroll
        for (int ksq = 0; ksq < 2; ++ksq) {
            bf16x8 a[4], b[4];
            #pragma unroll
            for (int mt = 0; mt < 4; ++mt) {
                int row = wm * 64 + mt * 16 + l16;
                a[mt] = *(const bf16x8*)&as[row * 64 + (((ksq * 4 + quad) ^ (l16 & 7)) * 8)];
            }
            #pragma unroll
            for (int nt = 0; nt < 4; ++nt) {
                int row = wn * 64 + nt * 16 + l16;
                b[nt] = *(const bf16x8*)&bs[row * 64 + (((ksq * 4 + quad) ^ (l16 & 7)) * 8)];
            }
            #pragma unroll
            for (int mt = 0; mt < 4; ++mt)
                #pragma unroll
                for (int nt = 0; nt < 4; ++nt)
                    acc[mt][nt] = __builtin_amdgcn_mfma_f32_16x16x32_bf16(a[mt], b[nt], acc[mt][nt], 0, 0, 0);
        }
    }

    #pragma unroll
    for (int mt = 0; mt < 4; ++mt)
        #pragma unroll
        for (int nt = 0; nt < 4; ++nt) {
            int e = n0 + wn * 64 + nt * 16 + l16;
            float bv = bias[e];
            #pragma unroll
            for (int r = 0; r < 4; ++r) {
                int m = m0 + wm * 64 + mt * 16 + quad * 4 + r;
                Yg[(size_t)m * 1024 + e] = acc[mt][nt][r] + bv;
            }
        }
}

extern "C" void kernel_launch(void* const* d_in, const int* in_sizes, int n_in,
                              void* d_out, int out_size, void* d_ws, size_t ws_size,
                              hipStream_t stream) {
    const float* Q    = (const float*)d_in[0];
    const float* K    = (const float*)d_in[1];
    const float* V    = (const float*)d_in[2];
    const float* W    = (const float*)d_in[3];
    const float* bias = (const float*)d_in[4];
    float* Y = (float*)d_out;

    unsigned short* Og = (unsigned short*)d_ws;                                     // 16 MiB
    unsigned short* Wb = (unsigned short*)((char*)d_ws + (size_t)16 * 1024 * 1024); // 2 MiB
    // Kb/Vb scratch in d_out (32 MiB) — dead before proj overwrites with Y
    unsigned short* Kb = (unsigned short*)d_out;
    unsigned short* Vb = Kb + (size_t)B_ * H_ * L_ * 64;

    conv_fused<<<1024 + 4096 + 2048, 256, 0, stream>>>(W, Wb, K, Kb, V, Vb);
    attn_kernel<<<B_ * H_ * (L_ / 128), 256, 0, stream>>>(Q, Kb, Vb, Og);
    proj_kernel<<<B_ * L_ / 128 * (D_ / 128), 256, 0, stream>>>(Og, Wb, bias, Y);
}

// Round 10
// 232.515 us; speedup vs baseline: 1.0468x; 1.0468x over previous
//
#include <hip/hip_runtime.h>
#include <hip/hip_bf16.h>

// B=4, L=2048, D=1024, H=16, HD=64. fp32 in/out.
// conv_fused (W/K/V fp32->bf16, V transposed, XOR-swizzle baked into global layout) ;
// attn (flash S^T form, 32x32 MFMA, KVBLK=64 dbuf 32KB, 4 waves — the measured-best r1
//       config: in-register softmax via cvt_pk_bf16 + permlane32_swap, VALU lsum) ;
// proj GEMM (BK=64, swizzled LDS, async gld dbuf, XCD-local m-panel remap).
// Kb/Vb scratch lives in d_out (dead before proj writes Y).

#define B_  4
#define L_  2048
#define D_  1024
#define H_  16

typedef float  f32x4  __attribute__((ext_vector_type(4)));
typedef float  f32x16 __attribute__((ext_vector_type(16)));
typedef short  bf16x8 __attribute__((ext_vector_type(8)));
typedef short  bf16x4 __attribute__((ext_vector_type(4)));

__device__ inline unsigned short f2bf(float x) {          // RNE
    union { float f; unsigned u; } v; v.f = x;
    unsigned r = v.u + 0x7FFFu + ((v.u >> 16) & 1u);
    return (unsigned short)(r >> 16);
}
__device__ inline float fast_exp2(float x) {
#if __has_builtin(__builtin_amdgcn_exp2f)
    return __builtin_amdgcn_exp2f(x);
#else
    return exp2f(x);
#endif
}
__device__ inline bf16x8 pack8s(float4 a, float4 b, float s) {
    bf16x8 r;
    r[0] = (short)f2bf(a.x * s); r[1] = (short)f2bf(a.y * s);
    r[2] = (short)f2bf(a.z * s); r[3] = (short)f2bf(a.w * s);
    r[4] = (short)f2bf(b.x * s); r[5] = (short)f2bf(b.y * s);
    r[6] = (short)f2bf(b.z * s); r[7] = (short)f2bf(b.w * s);
    return r;
}
__device__ inline unsigned cvtpk(float lo, float hi) {    // dword: lo16=bf16(lo), hi16=bf16(hi)
    unsigned r;
    asm("v_cvt_pk_bf16_f32 %0, %1, %2" : "=v"(r) : "v"(lo), "v"(hi));
    return r;
}
#define PSWAP(a, b) asm("v_permlane32_swap_b32 %0, %1" : "+v"(a), "+v"(b))

__device__ inline f32x16 zero16() {
    f32x16 z;
    #pragma unroll
    for (int i = 0; i < 16; ++i) z[i] = 0.f;
    return z;
}
__device__ inline void gld16(const void* g, void* l) {    // async global->LDS, 16B/lane
    __builtin_amdgcn_global_load_lds(
        (const __attribute__((address_space(1))) void*)g,
        (__attribute__((address_space(3))) void*)l, 16, 0, 0);
}

// ---------------- fused W/K/V fp32 -> bf16 conversions ----------------
// blocks [0,1024): W ; [1024,5120): K ; [5120,7168): V-transpose.
__global__ __launch_bounds__(256) void conv_fused(const float* __restrict__ W,
                                                  unsigned short* __restrict__ Wb,
                                                  const float* __restrict__ K,
                                                  unsigned short* __restrict__ Kb,
                                                  const float* __restrict__ V,
                                                  unsigned short* __restrict__ Vb) {
    __shared__ __align__(16) unsigned short T[64 * 72];  // convv transpose, [d][key] pad 72
    const int bid = blockIdx.x;
    const int tid = threadIdx.x;

    if (bid < 1024) {
        // ---- W ----
        int i = (bid * 256 + tid) * 4;
        float4 v = *(const float4*)&W[i];
        bf16x4 o;
        o[0] = (short)f2bf(v.x); o[1] = (short)f2bf(v.y);
        o[2] = (short)f2bf(v.z); o[3] = (short)f2bf(v.w);
        *(bf16x4*)&Wb[i] = o;
    } else if (bid < 5120) {
        // ---- K: [b,key,h,d], d-chunk XOR swizzle ----
        int o = (bid - 1024) * 256 + tid;            // octet index
        int d8 = o & 7; int h = (o >> 3) & 15; int key = (o >> 7) & 2047; int b = o >> 18;
        size_t base = ((size_t)(b * L_ + key) * H_ + h) * 64;
        const float* p = K + base + d8 * 8;
        float4 a = *(const float4*)p, c = *(const float4*)(p + 4);
        bf16x8 r;
        r[0] = (short)f2bf(a.x); r[1] = (short)f2bf(a.y); r[2] = (short)f2bf(a.z); r[3] = (short)f2bf(a.w);
        r[4] = (short)f2bf(c.x); r[5] = (short)f2bf(c.y); r[6] = (short)f2bf(c.z); r[7] = (short)f2bf(c.w);
        *(bf16x8*)&Kb[base + ((d8 * 8) ^ ((key & 7) * 8))] = r;
    } else {
        // ---- V transposed [b,h,d,key], coalesced reads ----
        int vb_ = bid - 5120;
        int kb_ = vb_ & 31, bh = vb_ >> 5;
        int b = bh >> 4, h = bh & 15, k0 = kb_ * 64;
        int kl = tid >> 4;
        int d4 = (tid & 15) * 4;
        #pragma unroll
        for (int pp = 0; pp < 4; ++pp) {
            int key = pp * 16 + kl;
            const float* p = V + ((size_t)(b * L_ + k0 + key)) * D_ + h * 64 + d4;
            float4 v = *(const float4*)p;    // coalesced: 16 lanes cover one 256B row
            T[(d4 + 0) * 72 + key] = f2bf(v.x);
            T[(d4 + 1) * 72 + key] = f2bf(v.y);
            T[(d4 + 2) * 72 + key] = f2bf(v.z);
            T[(d4 + 3) * 72 + key] = f2bf(v.w);
        }
        __syncthreads();
        #pragma unroll
        for (int i = 0; i < 2; ++i) {
            int c = i * 256 + tid; int d = c >> 3, ch = c & 7;
            bf16x8 v = *(const bf16x8*)&T[d * 72 + ch * 8];
            *(bf16x8*)&Vb[((size_t)(b * H_ + h) * 64 + d) * L_ + k0 + ((ch ^ (d & 7)) * 8)] = v;
        }
    }
}

// ---------------- flash attention (S^T form, 32x32 MFMA, KVBLK=64), 128 q/block ----------------
// Per wave: 32 q rows (q = l&31), KV tiles of 64 keys double-buffered in LDS (32 KB).
// S^T = K·Q^T via mfma_32x32x16: lane holds col q = l31, rows = keys (r&3)+8*(r>>2)+4*hl.
// P -> PV A-operand: cvt_pk pairs swapped via v_permlane32_swap. Row-sum lane-local (lsum).
// [measured r1: 88.7us; KVBLK=128 / ones-trick / setprio / 8-wave / 3buf-vmcnt all regress]
__global__ __launch_bounds__(256, 4) void attn_kernel(const float* __restrict__ Qg,
                                                      const unsigned short* __restrict__ Kb,
                                                      const unsigned short* __restrict__ Vb,
                                                      unsigned short* __restrict__ Og) {
    __shared__ __align__(16) unsigned short Ks[2][64 * 64];   // [key][d^swz]
    __shared__ __align__(16) unsigned short Vt[2][64 * 64];   // [d][key^swz]

    const int tid  = threadIdx.x;
    const int w    = tid >> 6;
    const int lane = tid & 63;
    const int l31  = lane & 31;
    const int hl   = lane >> 5;
    const int r7   = l31 & 7;

    // XCD swizzle: 16 q-blocks of one (b,h) on one XCD
    const int x   = blockIdx.x;
    const int idx = x >> 3;
    const int bh  = (x & 7) * 8 + (idx & 7);
    const int qb  = idx >> 3;
    const int bz  = bh >> 4;
    const int h   = bh & 15;
    const int q0  = qb * 128;

    const float qscale = 0.04508422f;           // log2(e)/32
    // Q as B-operand: lane needs Q[q0+w*32+l31][dstep*16 + hl*8 + 0..7]
    bf16x8 bq[4];
    {
        const int qrow = q0 + w * 32 + l31;
        const float* qp = Qg + ((size_t)(bz * L_ + qrow)) * D_ + h * 64 + hl * 8;
        #pragma unroll
        for (int dstep = 0; dstep < 4; ++dstep)
            bq[dstep] = pack8s(*(const float4*)(qp + dstep * 16),
                               *(const float4*)(qp + dstep * 16 + 4), qscale);
    }

    f32x16 o[2];
    o[0] = zero16(); o[1] = zero16();
    float lsum = 0.f;

    const unsigned short* Kbh = Kb + ((size_t)bz * L_ * H_ + h) * 64;  // + key*(H_*64)
    const unsigned short* Vbh = Vb + (size_t)(bz * H_ + h) * 64 * L_;  // + d*L_

    #define ISSUE(T, BUF)                                                           \
        {                                                                           \
            int k0_ = (T) * 64;                                                     \
            _Pragma("unroll")                                                       \
            for (int i = 0; i < 2; ++i) {                                           \
                int c = i * 256 + tid; int rr = c >> 3, jj = c & 7;                 \
                gld16(Kbh + (size_t)(k0_ + rr) * (H_ * 64) + jj * 8,                \
                      (char*)Ks[BUF] + (i * 256 + w * 64) * 16);                    \
                gld16(Vbh + (size_t)rr * L_ + k0_ + jj * 8,                         \
                      (char*)Vt[BUF] + (i * 256 + w * 64) * 16);                    \
            }                                                                       \
        }

    ISSUE(0, 0)

    for (int t = 0; t < 32; ++t) {
        __syncthreads();                        // drains this tile's DMA
        if (t < 31) ISSUE(t + 1, (t + 1) & 1)   // next tile in flight across compute
        const unsigned short* ks = Ks[t & 1];
        const unsigned short* vt = Vt[t & 1];

        #pragma unroll
        for (int kk = 0; kk < 2; ++kk) {        // key subtile: keys kk*32 + 0..31
            // ---- S^T = K Q^T : lane holds col q=l31, rows keyed by reg ----
            f32x16 s = zero16();
            #pragma unroll
            for (int dstep = 0; dstep < 4; ++dstep) {
                bf16x8 kf = *(const bf16x8*)&ks[(kk * 32 + l31) * 64 +
                                                ((((dstep << 1) | hl) ^ r7) << 3)];
                s = __builtin_amdgcn_mfma_f32_32x32x16_bf16(kf, bq[dstep], s, 0, 0, 0);
            }

            // ---- P = exp2(S^T); lane-local row-sum; pack to PV A-frags ----
            float p_[16];
            #pragma unroll
            for (int r = 0; r < 16; ++r) p_[r] = fast_exp2(s[r]);
            lsum += ((p_[0] + p_[1]) + (p_[2] + p_[3])) + ((p_[4] + p_[5]) + (p_[6] + p_[7]))
                  + ((p_[8] + p_[9]) + (p_[10] + p_[11])) + ((p_[12] + p_[13]) + (p_[14] + p_[15]));
            unsigned pk_[8];
            #pragma unroll
            for (int j = 0; j < 8; ++j) pk_[j] = cvtpk(p_[2 * j], p_[2 * j + 1]);
            // swap row-pair {X,X+1} with {X+8,X+9}: results are A-frag dwords 0 and 2
            PSWAP(pk_[0], pk_[2]); PSWAP(pk_[1], pk_[3]);   // frag 0: keys kk*32+0..15
            PSWAP(pk_[4], pk_[6]); PSWAP(pk_[5], pk_[7]);   // frag 1: keys kk*32+16..31
            union { unsigned u[4]; bf16x8 v; } a0_, a1_;
            a0_.u[0] = pk_[0]; a0_.u[1] = pk_[1]; a0_.u[2] = pk_[2]; a0_.u[3] = pk_[3];
            a1_.u[0] = pk_[4]; a1_.u[1] = pk_[5]; a1_.u[2] = pk_[6]; a1_.u[3] = pk_[7];

            // ---- O += P V ----
            #pragma unroll
            for (int kh = 0; kh < 2; ++kh) {
                const bf16x8 pf = kh ? a1_.v : a0_.v;
                const int kk2 = kk * 2 + kh;    // 16-key slot
                bf16x8 v0 = *(const bf16x8*)&vt[(l31) * 64 +
                                                ((((kk2 << 1) | hl) ^ r7) << 3)];
                bf16x8 v1 = *(const bf16x8*)&vt[(32 + l31) * 64 +
                                                ((((kk2 << 1) | hl) ^ r7) << 3)];
                o[0] = __builtin_amdgcn_mfma_f32_32x32x16_bf16(pf, v0, o[0], 0, 0, 0);
                o[1] = __builtin_amdgcn_mfma_f32_32x32x16_bf16(pf, v1, o[1], 0, 0, 0);
            }
        }
    }

    // ---- deferred row-sum completion + scaled store ----
    float tot = lsum + __shfl_xor(lsum, 32);    // lane holds full sum for q = l31
    float inv = 1.0f / tot;
    const size_t rowb0 = ((size_t)(bz * L_ + q0 + w * 32)) * D_ + h * 64;
    #pragma unroll
    for (int r = 0; r < 16; ++r) {
        const int qloc = (r & 3) + 8 * (r >> 2) + 4 * hl;
        const float invr = __shfl(inv, qloc);
        unsigned short* op = Og + rowb0 + (size_t)qloc * D_;
        op[l31]      = f2bf(o[0][r] * invr);
        op[32 + l31] = f2bf(o[1][r] * invr);
    }
}

// ---------------- projection: Y = O @ W^T + b, BK=64 swizzled, async dbuf ----------------
// 1D grid, XCD-local remap: all 8 n-blocks of one m-block share an XCD -> A-panel L2-resident.
__global__ __launch_bounds__(256, 2) void proj_kernel(const unsigned short* __restrict__ Og,
                                                      const unsigned short* __restrict__ Wb,
                                                      const float* __restrict__ bias,
                                                      float* __restrict__ Yg) {
    __shared__ unsigned short As[2][128 * 64];  // [row][64 shorts], chunk slot p holds octet p^(row&7)
    __shared__ unsigned short Bs[2][128 * 64];

    const int tid  = threadIdx.x;
    const int w    = tid >> 6;
    const int lane = tid & 63;
    const int l16  = lane & 15;
    const int quad = lane >> 4;
    const int wm   = w & 1, wn = w >> 1;

    const int bid = blockIdx.x;                 // 0..511
    const int jj_ = bid >> 3;                   // 0..63
    const int mb  = (bid & 7) + 8 * (jj_ >> 3); // 0..63 : same-m blocks share XCD
    const int nb  = jj_ & 7;                    // 0..7
    const int m0 = mb * 128;
    const int n0 = nb * 128;

    f32x4 acc[4][4];
    #pragma unroll
    for (int i = 0; i < 4; ++i)
        #pragma unroll
        for (int j = 0; j < 4; ++j) acc[i][j] = (f32x4){0.f, 0.f, 0.f, 0.f};

    #define PISSUE(T, BUF)                                                          \
        {                                                                           \
            int kt_ = (T) * 64;                                                     \
            _Pragma("unroll")                                                       \
            for (int i = 0; i < 4; ++i) {                                           \
                int c = i * 256 + tid; int row = c >> 3, p = c & 7;                 \
                int j = p ^ (row & 7);                                              \
                gld16(&Og[(size_t)(m0 + row) * 1024 + kt_ + j * 8],                 \
                      (char*)As[BUF] + (i * 256 + w * 64) * 16);                    \
                gld16(&Wb[(size_t)(n0 + row) * 1024 + kt_ + j * 8],                 \
                      (char*)Bs[BUF] + (i * 256 + w * 64) * 16);                    \
            }                                                                       \
        }

    PISSUE(0, 0)

    for (int t = 0; t < 16; ++t) {
        __syncthreads();
        if (t < 15) PISSUE(t + 1, (t + 1) & 1)
        const unsigned short* as = As[t & 1];
        const unsigned short* bs = Bs[t & 1];

        #pragma unroll
        for (int ksq = 0; ksq < 2; ++ksq) {
            bf16x8 a[4], b[4];
            #pragma unroll
            for (int mt = 0; mt < 4; ++mt) {
                int row = wm * 64 + mt * 16 + l16;
                a[mt] = *(const bf16x8*)&as[row * 64 + (((ksq * 4 + quad) ^ (l16 & 7)) * 8)];
            }
            #pragma unroll
            for (int nt = 0; nt < 4; ++nt) {
                int row = wn * 64 + nt * 16 + l16;
                b[nt] = *(const bf16x8*)&bs[row * 64 + (((ksq * 4 + quad) ^ (l16 & 7)) * 8)];
            }
            #pragma unroll
            for (int mt = 0; mt < 4; ++mt)
                #pragma unroll
                for (int nt = 0; nt < 4; ++nt)
                    acc[mt][nt] = __builtin_amdgcn_mfma_f32_16x16x32_bf16(a[mt], b[nt], acc[mt][nt], 0, 0, 0);
        }
    }

    #pragma unroll
    for (int mt = 0; mt < 4; ++mt)
        #pragma unroll
        for (int nt = 0; nt < 4; ++nt) {
            int e = n0 + wn * 64 + nt * 16 + l16;
            float bv = bias[e];
            #pragma unroll
            for (int r = 0; r < 4; ++r) {
                int m = m0 + wm * 64 + mt * 16 + quad * 4 + r;
                Yg[(size_t)m * 1024 + e] = acc[mt][nt][r] + bv;
            }
        }
}

extern "C" void kernel_launch(void* const* d_in, const int* in_sizes, int n_in,
                              void* d_out, int out_size, void* d_ws, size_t ws_size,
                              hipStream_t stream) {
    const float* Q    = (const float*)d_in[0];
    const float* K    = (const float*)d_in[1];
    const float* V    = (const float*)d_in[2];
    const float* W    = (const float*)d_in[3];
    const float* bias = (const float*)d_in[4];
    float* Y = (float*)d_out;

    unsigned short* Og = (unsigned short*)d_ws;                                     // 16 MiB
    unsigned short* Wb = (unsigned short*)((char*)d_ws + (size_t)16 * 1024 * 1024); // 2 MiB
    // Kb/Vb scratch in d_out (32 MiB) — dead before proj overwrites with Y
    unsigned short* Kb = (unsigned short*)d_out;
    unsigned short* Vb = Kb + (size_t)B_ * H_ * L_ * 64;

    conv_fused<<<1024 + 4096 + 2048, 256, 0, stream>>>(W, Wb, K, Kb, V, Vb);
    attn_kernel<<<B_ * H_ * (L_ / 128), 256, 0, stream>>>(Q, Kb, Vb, Og);
    proj_kernel<<<B_ * L_ / 128 * (D_ / 128), 256, 0, stream>>>(Og, Wb, bias, Y);
}